// Round 9
// baseline (334.299 us; speedup 1.0000x reference)
//
#include <hip/hip_runtime.h>

// B=128, C_IN=128, C_HID=256, C_OUT=128, H*W=1600, E=8, TOP_K=2.
#define CIN   128
#define CHID  256
#define COUT  128
#define HWPX  1600
#define NT    50      // 32-px tiles per batch image
#define TPX   32
#define XOFF  0       // LDS shorts: x tiles [0, 13*4096)
#define WOFF  53248   // LDS shorts: weight dbuf [53248, 53248+2*8192)

typedef __attribute__((ext_vector_type(8))) short bf16x8;  // 8 bf16 = 4 VGPRs
typedef __attribute__((ext_vector_type(4))) float f32x4;   // MFMA C/D

__device__ __forceinline__ unsigned short f2bf(float f) {
  unsigned int u = __builtin_bit_cast(unsigned int, f);
  u += 0x7FFFu + ((u >> 16) & 1u);
  return (unsigned short)(u >> 16);
}
__device__ __forceinline__ unsigned int pack_bf2(float a, float b) {
  return (unsigned int)f2bf(a) | ((unsigned int)f2bf(b) << 16);
}
// Fast SiLU: v_exp_f32 + v_rcp_f32 (~1e-7 rel err, invisible under bf16).
__device__ __forceinline__ unsigned int silu_gate_pk(float a, float b, float g) {
  const float ea = __builtin_amdgcn_exp2f(a * -1.442695041f);
  const float eb = __builtin_amdgcn_exp2f(b * -1.442695041f);
  const float sa = g * a * __builtin_amdgcn_rcpf(1.0f + ea);
  const float sb = g * b * __builtin_amdgcn_rcpf(1.0f + eb);
  return pack_bf2(sa, sb);
}

// Async 8 KB linear tile stage: 8 x global_load_lds_dwordx4 (verified r4).
__device__ __forceinline__ void stage_tile(const unsigned short* g,
                                           unsigned short* l, int lane) {
#pragma unroll
  for (int k = 0; k < 8; ++k)
    __builtin_amdgcn_global_load_lds(
        (const __attribute__((address_space(1))) unsigned int*)(g + (k * 64 + lane) * 8),
        (__attribute__((address_space(3))) unsigned int*)(l + k * 512),
        16, 0, 0);
}

// Async stage of one 16 KB weight slice (W1 8 KB + W2 8 KB) into LDS via
// global_load_lds (verified r6): 4 loads per wave.
__device__ __forceinline__ void stage_w(const unsigned short* W1b,
                                        const unsigned short* W2b,
                                        int e, int grp, unsigned short* wb,
                                        int wave, int lane) {
  const long s = ((long)(e * 8 + grp) << 12) + wave * 1024 + lane * 8;
#pragma unroll
  for (int k2 = 0; k2 < 2; ++k2) {
    __builtin_amdgcn_global_load_lds(
        (const __attribute__((address_space(1))) unsigned int*)(W1b + s + k2 * 512),
        (__attribute__((address_space(3))) unsigned int*)(wb + wave * 1024 + k2 * 512),
        16, 0, 0);
    __builtin_amdgcn_global_load_lds(
        (const __attribute__((address_space(1))) unsigned int*)(W2b + s + k2 * 512),
        (__attribute__((address_space(3))) unsigned int*)(wb + 4096 + wave * 1024 + k2 * 512),
        16, 0, 0);
  }
}

// ---------------------------------------------------------------------------
// Combined converter.
//  blocks [0,1664): fp32 x -> bf16 tile fragment-images (verified r4),
//    layout incl. rotation slot=(chunk+px)&15, tiles stored contiguously:
//    xbf[(b*50 + t)*4096 + (p*16+slot)*8 + j].
//  blocks [1664,2688): weights -> LDS-slice-image layouts (verified r1):
//    W1b: [e][grp][512][8], p = r*16 + ((c + r) & 15)  (h-trick rows)
//    W2b: [e][grp][512][8], p = co*4 + ((c + co + (co>>2)) & 3)
// ---------------------------------------------------------------------------
__global__ __launch_bounds__(256) void convert_kernel(
    const float* __restrict__ x, const float* __restrict__ W1,
    const float* __restrict__ W2, unsigned short* __restrict__ W1b,
    unsigned short* __restrict__ W2b, unsigned short* __restrict__ xbf) {
  __shared__ __align__(16) unsigned short xl[4][4096];
  const int bid = blockIdx.x;
  if (bid < 1664) {
    const int wave = threadIdx.x >> 6, lane = threadIdx.x & 63;
    const int b = bid / 13, blk = bid % 13;
    const int tile = blk * 4 + wave;
    if (tile >= NT) return;
    const int p = lane & 31, hh = lane >> 5;
    const float* xr = x + (long)b * CIN * HWPX + tile * TPX + p;
    unsigned short* w = &xl[wave][0];
#pragma unroll
    for (int c = 0; c < 8; ++c) {
      const int cc = c * 2 + hh;               // cin chunk 0..15
      float v[8];
#pragma unroll
      for (int jj = 0; jj < 8; ++jj) v[jj] = xr[(long)(cc * 8 + jj) * HWPX];
      union { bf16x8 t; unsigned int u[4]; } t;
#pragma unroll
      for (int d = 0; d < 4; ++d) t.u[d] = pack_bf2(v[2 * d], v[2 * d + 1]);
      const int slot = (cc + p) & 15;          // rotation (bank spread)
      *reinterpret_cast<bf16x8*>(&w[(p * 16 + slot) * 8]) = t.t;
    }
    // linear flush (wave-internal DS FIFO), coalesced 1 KB stores
    uint4* dst = reinterpret_cast<uint4*>(xbf + ((long)b * NT + tile) * 4096);
    const uint4* src = reinterpret_cast<const uint4*>(w);
#pragma unroll
    for (int k = 0; k < 8; ++k) dst[k * 64 + lane] = src[k * 64 + lane];
    return;
  }
  const int wb2 = bid - 1664;                  // 0..1023
  const int i   = wb2 * 256 + threadIdx.x;     // 0 .. 262143
  const int j   = i & 7;
  const int p   = (i >> 3) & 511;
  const int grp = (i >> 12) & 7;
  const int e   = i >> 15;
  {
    const int r   = p >> 4;
    const int c   = ((p & 15) - r) & 15;
    const int row = r & 15, mt = r >> 4;
    const int ch  = grp * 32 + ((row >> 2) << 3) + (row & 3) + (mt << 2);
    W1b[i] = f2bf(W1[(e * CHID + ch) * CIN + c * 8 + j]);
  }
  {
    const int co = p >> 2;
    const int c  = ((p & 3) - co - (co >> 2)) & 3;
    const int ch = grp * 32 + c * 8 + j;
    W2b[i] = f2bf(W2[(e * COUT + co) * CHID + ch]);
  }
}

// ---------------------------------------------------------------------------
// moe v8: v6's verified skeleton (1 block/CU, gs-outer/tile-inner, counted
// vmcnt(4) weight dbuf, fragment hoist, x4-tile reuse) with two changes:
//  - x staged ONCE, LINEARLY (104 KB of packed bf16 tile-images via
//    global_load_lds) instead of strided fp32 VALU staging;
//  - epilogue emits 384-512 B contiguous runs per out row (per-mt transpose
//    of all tiles into wave-private scratch, then row-pair run stores).
// ---------------------------------------------------------------------------
__global__ __launch_bounds__(256, 1) void moe_kernel(
    const unsigned short* __restrict__ xbf, const float* __restrict__ wts,
    const int* __restrict__ idx, const unsigned short* __restrict__ W1b,
    const float* __restrict__ b1, const unsigned short* __restrict__ W2b,
    const float* __restrict__ b2, float* __restrict__ out) {
  __shared__ __align__(16) unsigned short lds[69632];   // 136 KB

  const int tid  = threadIdx.x;
  const int wave = tid >> 6;
  const int lane = tid & 63;
  const int q    = lane >> 4;
  const int r16  = lane & 15;

  const int b    = blockIdx.x >> 2;
  const int blkp = blockIdx.x & 3;
  const int cnt  = (blkp < 2) ? 13 : 12;               // tiles in this block
  const int T0   = blkp * 12 + (blkp < 2 ? blkp : 2);  // first global tile
  const int ntw  = 3 + ((cnt == 13 && wave == 0) ? 1 : 0);
  const int ws   = 3 * wave + ((cnt == 13 && wave > 0) ? 1 : 0);

  const int   e0 = __builtin_amdgcn_readfirstlane(idx[b * 2 + 0]);
  const int   e1 = __builtin_amdgcn_readfirstlane(idx[b * 2 + 1]);
  const float g0 = wts[b * 2 + 0], g1 = wts[b * 2 + 1];

  // ---- prologue stages. Order matters for the vmcnt(4) gate at gs=0:
  //      w(0) [4 loads], x [8*ntw loads], w(1) [4 loads] -> vmcnt(4) at gs=0
  //      guarantees w(0)+x landed while w(1)'s 4 loads stay in flight.
  stage_w(W1b, W2b, e0, 0, &lds[WOFF + 0 * 8192], wave, lane);
  for (int lt = ws; lt < ws + ntw; ++lt)
    stage_tile(xbf + ((long)b * NT + (T0 + lt)) * 4096,
               &lds[XOFF + lt * 4096], lane);
  stage_w(W1b, W2b, e0, 1, &lds[WOFF + 1 * 8192], wave, lane);

  f32x4 accO[4][8][2];
#pragma unroll
  for (int t = 0; t < 4; ++t)
#pragma unroll
    for (int mt = 0; mt < 8; ++mt)
#pragma unroll
      for (int nt = 0; nt < 2; ++nt) accO[t][mt][nt] = (f32x4){0.f, 0.f, 0.f, 0.f};

  for (int gs = 0; gs < 16; ++gs) {
    const int   sl  = gs >> 3;
    const int   grp = gs & 7;
    const int   e   = sl ? e1 : e0;
    const float g   = sl ? g1 : g0;
    unsigned short* wb = &lds[WOFF + (gs & 1) * 8192];

    // gate: stage(gs) landed (stage(gs+1)'s 4 loads may fly); raw barrier.
    asm volatile("s_waitcnt vmcnt(4)" ::: "memory");
    __builtin_amdgcn_sched_barrier(0);
    __builtin_amdgcn_s_barrier();

    // ---- hoist this slice's fragments into VGPRs (shared by all tiles)
    bf16x8 w1f[8];
#pragma unroll
    for (int ks = 0; ks < 4; ++ks) {
      const int slotw = (ks * 4 + q + r16) & 15;
      w1f[ks * 2 + 0] = *reinterpret_cast<const bf16x8*>(&wb[(r16 * 16 + slotw) * 8]);
      w1f[ks * 2 + 1] = *reinterpret_cast<const bf16x8*>(&wb[((r16 + 16) * 16 + slotw) * 8]);
    }
    bf16x8 w2f[8];
#pragma unroll
    for (int mt = 0; mt < 8; ++mt) {
      const int co = mt * 16 + r16;
      w2f[mt] = *reinterpret_cast<const bf16x8*>(
          &wb[4096 + (co * 4 + ((q + co + (co >> 2)) & 3)) * 8]);
    }
    const float* b1e = b1 + e * CHID + grp * 32;
    const f32x4 bA = *reinterpret_cast<const f32x4*>(&b1e[q * 8]);
    const f32x4 bB = *reinterpret_cast<const f32x4*>(&b1e[q * 8 + 4]);

    // ---- 3-4 tiles through this weight slice
#pragma unroll
    for (int t = 0; t < 4; ++t) {
      if (t < ntw) {
        const unsigned short* xw = &lds[XOFF + (ws + t) * 4096];
        f32x4 aA[2], aB[2];
#pragma unroll
        for (int nt = 0; nt < 2; ++nt) {
          aA[nt] = (f32x4){0.f, 0.f, 0.f, 0.f};
          aB[nt] = (f32x4){0.f, 0.f, 0.f, 0.f};
        }
#pragma unroll
        for (int ks = 0; ks < 4; ++ks) {
#pragma unroll
          for (int nt = 0; nt < 2; ++nt) {
            const int px = nt * 16 + r16;
            const bf16x8 xf = *reinterpret_cast<const bf16x8*>(
                &xw[(px * 16 + ((ks * 4 + q + px) & 15)) * 8]);
            aA[nt] = __builtin_amdgcn_mfma_f32_16x16x32_bf16(w1f[ks * 2 + 0], xf, aA[nt], 0, 0, 0);
            aB[nt] = __builtin_amdgcn_mfma_f32_16x16x32_bf16(w1f[ks * 2 + 1], xf, aB[nt], 0, 0, 0);
          }
        }
        union { bf16x8 v; unsigned int u[4]; } h[2];
#pragma unroll
        for (int nt = 0; nt < 2; ++nt) {
          h[nt].u[0] = silu_gate_pk(aA[nt][0] + bA[0], aA[nt][1] + bA[1], g);
          h[nt].u[1] = silu_gate_pk(aA[nt][2] + bA[2], aA[nt][3] + bA[3], g);
          h[nt].u[2] = silu_gate_pk(aB[nt][0] + bB[0], aB[nt][1] + bB[1], g);
          h[nt].u[3] = silu_gate_pk(aB[nt][2] + bB[2], aB[nt][3] + bB[3], g);
        }
#pragma unroll
        for (int mt = 0; mt < 8; ++mt)
#pragma unroll
          for (int nt = 0; nt < 2; ++nt)
            accO[t][mt][nt] = __builtin_amdgcn_mfma_f32_16x16x32_bf16(w2f[mt], h[nt].v, accO[t][mt][nt], 0, 0, 0);
      }
    }

    // all waves done reading wb -> safe to restage this buffer.
    __builtin_amdgcn_s_barrier();
    if (gs <= 14) {
      const int gs2 = (gs + 2 <= 15) ? gs + 2 : 15;    // gs=14: dup keeps
      const int e2  = (gs2 >> 3) ? e1 : e0;            // vmcnt gate exact
      stage_w(W1b, W2b, e2, gs2 & 7, wb, wave, lane);
    }
  }

  // ---- epilogue: per-mt transpose of ALL tiles into wave-private scratch
  //      (dead x region; wave-internal DS FIFO -> no barriers), then
  //      row-pair stores walking px across tiles: 384-512 B runs per row.
  float* scr = reinterpret_cast<float*>(&lds[XOFF + ws * 4096]); // 4*528 f32
  const float* b2e0 = b2 + e0 * COUT;
  const float* b2e1 = b2 + e1 * COUT;
  const int rh   = lane >> 5;                  // row of pair
  const int li   = lane & 31;
  const int tt   = li >> 3;                    // tile within span
  const int px4v = (li & 7) * 4;               // px quad within tile
  const long ob  = (long)b * COUT * HWPX + (long)(T0 + ws) * TPX;
#pragma unroll
  for (int mt = 0; mt < 8; ++mt) {
    const int coW = q * 4;
    const f32x4 bias = g0 * (*reinterpret_cast<const f32x4*>(&b2e0[mt * 16 + coW])) +
                       g1 * (*reinterpret_cast<const f32x4*>(&b2e1[mt * 16 + coW]));
#pragma unroll
    for (int t = 0; t < 4; ++t) {
      if (t < ntw) {
#pragma unroll
        for (int nt = 0; nt < 2; ++nt) {
          const f32x4 v = accO[t][mt][nt] + bias;
#pragma unroll
          for (int rr = 0; rr < 4; ++rr)
            scr[t * 528 + (coW + rr) * 33 + nt * 16 + r16] = v[rr];
        }
      }
    }
    if (tt < ntw) {
      const float* sb = scr + tt * 528;
#pragma unroll
      for (int cp = 0; cp < 8; ++cp) {
        const int col = cp * 2 + rh;           // co within mt-group
        const float4 v = *reinterpret_cast<const float4*>(&sb[col * 33 + px4v]);
        *reinterpret_cast<float4*>(
            &out[ob + (long)(mt * 16 + col) * HWPX + tt * TPX + px4v]) = v;
      }
    }
  }
}

extern "C" void kernel_launch(void* const* d_in, const int* in_sizes, int n_in,
                              void* d_out, int out_size, void* d_ws, size_t ws_size,
                              hipStream_t stream) {
  const float* x   = (const float*)d_in[0];
  const float* wts = (const float*)d_in[1];
  const int*   idx = (const int*)d_in[2];
  const float* W1  = (const float*)d_in[3];
  const float* b1  = (const float*)d_in[4];
  const float* W2  = (const float*)d_in[5];
  const float* b2  = (const float*)d_in[6];
  float* out = (float*)d_out;

  unsigned short* W1b = (unsigned short*)d_ws;            // 262144 shorts
  unsigned short* W2b = W1b + 8 * CHID * CIN;             // 262144 shorts
  unsigned short* xbf = W2b + 8 * CHID * CIN;             // 128*50*4096 shorts

  convert_kernel<<<1664 + 1024, 256, 0, stream>>>(x, W1, W2, W1b, W2b, xbf);
  moe_kernel<<<128 * 4, 256, 0, stream>>>(xbf, wts, idx, W1b, b1, W2b, b2, out);
}